// Round 10
// baseline (637.208 us; speedup 1.0000x reference)
//
#include <hip/hip_runtime.h>

typedef unsigned short u16;
typedef u16 u16x4 __attribute__((ext_vector_type(4)));
typedef u16 u16x8 __attribute__((ext_vector_type(8)));
typedef float f32x4 __attribute__((ext_vector_type(4)));
typedef __bf16 bf16x8 __attribute__((ext_vector_type(8)));

#define S_LEN 2048
#define HIDDEN_D 4096
#define NHEADS 32
#define QLORA 1536
#define KVLORA 512
#define ROPED 64
#define NOPED 128
#define VDIM 128
#define QHD 192
#define SCALING_F 0.07216878364870323f

#define GLOBAL_U32 const __attribute__((address_space(1))) unsigned int
#define LDS_U32 __attribute__((address_space(3))) unsigned int

__device__ __forceinline__ u16 f2bf(float x) {
  union { float f; unsigned u; } v; v.f = x;
  unsigned r = v.u + 0x7fffu + ((v.u >> 16) & 1u);
  return (u16)(r >> 16);
}
__device__ __forceinline__ float bf2f(u16 x) {
  union { unsigned u; float f; } v; v.u = ((unsigned)x) << 16; return v.f;
}

__device__ __forceinline__ f32x4 mfma_bf16(u16x8 a, u16x8 b, f32x4 c) {
  return __builtin_amdgcn_mfma_f32_16x16x32_bf16(
      __builtin_bit_cast(bf16x8, a), __builtin_bit_cast(bf16x8, b), c, 0, 0, 0);
}

// ---------------- fp32 -> bf16 convert (vector) ----------------
__global__ __launch_bounds__(256) void cvt_kernel(const float* __restrict__ in,
                                                  u16* __restrict__ out, int n4) {
  int i = blockIdx.x * 256 + threadIdx.x;
  if (i >= n4) return;
  f32x4 v = ((const f32x4*)in)[i];
  u16x4 o;
  o[0] = f2bf(v[0]); o[1] = f2bf(v[1]); o[2] = f2bf(v[2]); o[3] = f2bf(v[3]);
  ((u16x4*)out)[i] = o;
}

// ============ GEMM core: m97 structure — global_load_lds w16, single 32KB buffer,
// 2-barrier K-loop, no staging VGPRs (occupancy-driven latency hiding). ============

#define GEMM_PROLOGUE()                                                        \
  __shared__ u16 sA[128 * 64];                                                 \
  __shared__ u16 sB[128 * 64];                                                 \
  const int tid = threadIdx.x;                                                 \
  const int wid = tid >> 6, lane = tid & 63;                                   \
  const int lr = lane & 15, lg = lane >> 4;                                    \
  const int nbn = (N + 127) >> 7;                                              \
  const int bx = blockIdx.x % nbn, by = blockIdx.x / nbn;                      \
  const int bm = by << 7, bn = bx << 7;                                        \
  const int wm = (wid >> 1) << 6, wn = (wid & 1) << 6;                         \
  const int kbase = blockIdx.y * Ks;                                           \
  f32x4 acc[4][4] = {};                                                        \
  const int nk = Ks >> 6;                                                      \
  for (int t = 0; t < nk; ++t) {                                               \
    const int k0 = kbase + (t << 6);                                           \
    _Pragma("unroll")                                                          \
    for (int i = 0; i < 4; ++i) {                                              \
      int chunk = i * 256 + tid;                                               \
      int row = chunk >> 3, c8 = chunk & 7;                                    \
      int gr = bm + row; if (gr >= M) gr = M - 1;                              \
      const u16* gp = A + (size_t)gr * lda + k0 + (c8 << 3);                   \
      __builtin_amdgcn_global_load_lds((GLOBAL_U32*)gp, (LDS_U32*)&sA[chunk * 8], 16, 0, 0); \
    }                                                                          \
    _Pragma("unroll")                                                          \
    for (int i = 0; i < 4; ++i) {                                              \
      int chunk = i * 256 + tid;                                               \
      int row = chunk >> 3, c8 = chunk & 7;                                    \
      int gn = bn + row; if (gn >= N) gn = N - 1;                              \
      const u16* gp = B + (size_t)gn * ldb + k0 + (c8 << 3);                   \
      __builtin_amdgcn_global_load_lds((GLOBAL_U32*)gp, (LDS_U32*)&sB[chunk * 8], 16, 0, 0); \
    }                                                                          \
    __syncthreads();                                                           \
    _Pragma("unroll")                                                          \
    for (int ks = 0; ks < 2; ++ks) {                                           \
      const int kof = ks * 32 + lg * 8;                                        \
      u16x8 av[4], bv[4];                                                      \
      _Pragma("unroll")                                                        \
      for (int m = 0; m < 4; ++m) av[m] = *(const u16x8*)&sA[(wm + m * 16 + lr) * 64 + kof]; \
      _Pragma("unroll")                                                        \
      for (int n = 0; n < 4; ++n) bv[n] = *(const u16x8*)&sB[(wn + n * 16 + lr) * 64 + kof]; \
      _Pragma("unroll")                                                        \
      for (int m = 0; m < 4; ++m)                                              \
        _Pragma("unroll")                                                      \
        for (int n = 0; n < 4; ++n)                                            \
          acc[m][n] = mfma_bf16(av[m], bv[n], acc[m][n]);                      \
    }                                                                          \
    __syncthreads();                                                           \
  }

// ---------------- GEMM -> fp32 C (q_a, kv_a, w_o) ----------------
__global__ __launch_bounds__(256) void gemm_ff(
    const u16* __restrict__ A, const u16* __restrict__ B, float* __restrict__ C,
    int M, int N, int Ks, int lda, int ldb, int ldc)
{
  C += (size_t)blockIdx.y * M * ldc;
  GEMM_PROLOGUE()
#pragma unroll
  for (int m = 0; m < 4; ++m) {
    const int row0 = bm + wm + m * 16 + (lg << 2);
#pragma unroll
    for (int n = 0; n < 4; ++n) {
      const int col = bn + wn + n * 16 + lr;
      if (col < N) {
#pragma unroll
        for (int r = 0; r < 4; ++r)
          C[(size_t)(row0 + r) * ldc + col] = acc[m][n][r];
      }
    }
  }
}

// ---------------- GEMM -> bf16 C (q_b) ----------------
__global__ __launch_bounds__(256) void gemm_fb(
    const u16* __restrict__ A, const u16* __restrict__ B, u16* __restrict__ C,
    int M, int N, int Ks, int lda, int ldb, int ldc)
{
  GEMM_PROLOGUE()
#pragma unroll
  for (int m = 0; m < 4; ++m) {
    const int row0 = bm + wm + m * 16 + (lg << 2);
#pragma unroll
    for (int n = 0; n < 4; ++n) {
      const int col = bn + wn + n * 16 + lr;
#pragma unroll
      for (int r = 0; r < 4; ++r)
        C[(size_t)(row0 + r) * ldc + col] = f2bf(acc[m][n][r]);
    }
  }
}

// ---------------- kv_b GEMM with fused split+transpose epilogue ----------------
// C[s][h*256+c]: c<128 -> Knope[(h*2048+s)*128+c]; c>=128 -> Vt[(h*128+c-128)*2048+s].
__global__ __launch_bounds__(256) void gemm_kvb(
    const u16* __restrict__ A, const u16* __restrict__ B,
    u16* __restrict__ Knope, u16* __restrict__ Vt,
    int M, int N, int Ks, int lda, int ldb)
{
  GEMM_PROLOGUE()
#pragma unroll
  for (int m = 0; m < 4; ++m) {
    const int row0 = bm + wm + m * 16 + (lg << 2);
#pragma unroll
    for (int n = 0; n < 4; ++n) {
      const int col = bn + wn + n * 16 + lr;
      const int h = col >> 8, c = col & 255;
      if (c < 128) {
#pragma unroll
        for (int r = 0; r < 4; ++r)
          Knope[((size_t)h * 2048 + row0 + r) * 128 + c] = f2bf(acc[m][n][r]);
      } else {
        u16x4 v;
        v[0] = f2bf(acc[m][n][0]); v[1] = f2bf(acc[m][n][1]);
        v[2] = f2bf(acc[m][n][2]); v[3] = f2bf(acc[m][n][3]);
        *(u16x4*)&Vt[((size_t)h * 128 + (c - 128)) * 2048 + row0] = v;
      }
    }
  }
}

// ---------------- RMS norm rows over summed split-K partials (fp32 -> bf16) ----------------
__global__ __launch_bounds__(256) void rms_kernel(const float* __restrict__ X,
                                                  const float* __restrict__ w,
                                                  u16* __restrict__ out, int D,
                                                  int nparts, size_t pstride) {
  const int row = blockIdx.x;
  const float* x = X + (size_t)row * D;
  __shared__ float sb[4];
  float ss = 0.f;
  for (int i = threadIdx.x * 4; i < D; i += 1024) {
    f32x4 v = *(const f32x4*)&x[i];
    for (int pp = 1; pp < nparts; ++pp) {
      f32x4 v2 = *(const f32x4*)&x[pp * pstride + i];
      v[0] += v2[0]; v[1] += v2[1]; v[2] += v2[2]; v[3] += v2[3];
    }
    ss += v[0] * v[0] + v[1] * v[1] + v[2] * v[2] + v[3] * v[3];
  }
#pragma unroll
  for (int off = 32; off >= 1; off >>= 1) ss += __shfl_xor(ss, off, 64);
  if ((threadIdx.x & 63) == 0) sb[threadIdx.x >> 6] = ss;
  __syncthreads();
  const float inv = rsqrtf((sb[0] + sb[1] + sb[2] + sb[3]) / (float)D + 1e-6f);
  u16* o = out + (size_t)row * D;
  for (int i = threadIdx.x * 4; i < D; i += 1024) {
    f32x4 v = *(const f32x4*)&x[i];
    for (int pp = 1; pp < nparts; ++pp) {
      f32x4 v2 = *(const f32x4*)&x[pp * pstride + i];
      v[0] += v2[0]; v[1] += v2[1]; v[2] += v2[2]; v[3] += v2[3];
    }
    f32x4 wv = *(const f32x4*)&w[i];
    u16x4 u;
    u[0] = f2bf(v[0] * inv * wv[0]); u[1] = f2bf(v[1] * inv * wv[1]);
    u[2] = f2bf(v[2] * inv * wv[2]); u[3] = f2bf(v[3] * inv * wv[3]);
    *(u16x4*)&o[i] = u;
  }
}

// ---------------- ckv epilogue over 4 split-K partials: RMS(512) + rope(64) ----------------
__global__ __launch_bounds__(256) void ckv_epi_kernel(const float* __restrict__ ckv,
    const float* __restrict__ w, const float* __restrict__ cosp, const float* __restrict__ sinp,
    u16* __restrict__ klatn, u16* __restrict__ krot, int nparts, size_t pstride) {
  const int s = blockIdx.x;
  const float* x = ckv + (size_t)s * 576;
  __shared__ float sb[4];
  const int i2 = threadIdx.x * 2;
  float a = 0.f, b = 0.f;
  for (int pp = 0; pp < nparts; ++pp) {
    a += x[pp * pstride + i2];
    b += x[pp * pstride + i2 + 1];
  }
  float ss = a * a + b * b;
#pragma unroll
  for (int off = 32; off >= 1; off >>= 1) ss += __shfl_xor(ss, off, 64);
  if ((threadIdx.x & 63) == 0) sb[threadIdx.x >> 6] = ss;
  __syncthreads();
  const float inv = rsqrtf((sb[0] + sb[1] + sb[2] + sb[3]) / 512.0f + 1e-6f);
  klatn[(size_t)s * 512 + i2]     = f2bf(a * inv * w[i2]);
  klatn[(size_t)s * 512 + i2 + 1] = f2bf(b * inv * w[i2 + 1]);
  if (threadIdx.x < 64) {
    const int d = threadIdx.x;
    float xr = 0.f, rrabs = 0.f;
    for (int pp = 0; pp < nparts; ++pp) {
      xr += x[pp * pstride + 512 + d];
      rrabs += x[pp * pstride + 512 + ((d < 32) ? (d + 32) : (d - 32))];
    }
    const float rr = (d < 32) ? -rrabs : rrabs;
    krot[(size_t)s * 64 + d] = f2bf(xr * cosp[s * 64 + d] + rr * sinp[s * 64 + d]);
  }
}

// ---------------- q epilogue (bf16 in): rope + scale + [rope|nope] layout, bf16 ----------------
__global__ __launch_bounds__(256) void q_epi_kernel(const u16* __restrict__ q_raw,
    const float* __restrict__ cosp, const float* __restrict__ sinp, u16* __restrict__ Qb) {
  const int s = blockIdx.x;
  const u16* x = q_raw + (size_t)s * 6144;
  for (int idx = threadIdx.x; idx < 6144; idx += 256) {
    const int h = idx / 192, d = idx - h * 192;
    float v;
    if (d < 64) {
      const float xr = bf2f(x[h * 192 + 128 + d]);
      const float rr = (d < 32) ? -bf2f(x[h * 192 + 160 + d]) : bf2f(x[h * 192 + 96 + d]);
      v = xr * cosp[s * 64 + d] + rr * sinp[s * 64 + d];
    } else {
      v = bf2f(x[h * 192 + d - 64]);
    }
    Qb[((size_t)h * 2048 + s) * QHD + d] = f2bf(v * SCALING_F);
  }
}

// ---------------- flash attention (causal), 4 waves, QBLK=128, KVBLK=64 ----------------
// EXACT R1/R8 structure (measured 250us / 40MB fetch): linear LDS, natural block
// order, no setprio, no barrier. DO NOT MODIFY — fragile cache-lockstep regime.
__global__ __launch_bounds__(256, 2) void flash_kernel(
    const u16* __restrict__ Qb, const u16* __restrict__ Krot,
    const u16* __restrict__ Knope, const u16* __restrict__ Vt,
    u16* __restrict__ attnb)
{
  const int h = blockIdx.x & 31, qt = blockIdx.x >> 5;
  const int q0 = qt << 7;
  __shared__ u16 sK[64][QHD];      // [kv][rope(64)|nope(128)]
  __shared__ u16 sV[VDIM][64];     // V^T [d][kv]
  __shared__ u16 sP[4][32][64];    // per-wave P
  const int tid = threadIdx.x;
  const int wid = tid >> 6, lane = tid & 63;
  const int lr = lane & 15, lg = lane >> 4;

  u16x8 qf[2][6];
#pragma unroll
  for (int m = 0; m < 2; ++m) {
    const int row = q0 + wid * 32 + m * 16 + lr;
#pragma unroll
    for (int kk = 0; kk < 6; ++kk)
      qf[m][kk] = *(const u16x8*)&Qb[((size_t)h * 2048 + row) * QHD + kk * 32 + lg * 8];
  }

  f32x4 acc[2][8] = {};
  float mx[2][4], ls[2][4];
#pragma unroll
  for (int m = 0; m < 2; ++m)
#pragma unroll
    for (int r = 0; r < 4; ++r) { mx[m][r] = -1e30f; ls[m][r] = 0.f; }

  const int nkv = q0 + 128;
  u16x8 kreg[6], vreg[4];

  auto loadKV = [&](int kv0) {
#pragma unroll
    for (int i = 0; i < 6; ++i) {
      const int chunk = i * 256 + tid;
      const int row = chunk / 24, cc = chunk % 24;
      const u16* src = (cc < 8)
          ? &Krot[(size_t)(kv0 + row) * 64 + cc * 8]
          : &Knope[((size_t)h * 2048 + kv0 + row) * 128 + (cc - 8) * 8];
      kreg[i] = *(const u16x8*)src;
    }
#pragma unroll
    for (int i = 0; i < 4; ++i) {
      const int chunk = i * 256 + tid;
      const int d = chunk >> 3, c = chunk & 7;
      vreg[i] = *(const u16x8*)&Vt[((size_t)h * VDIM + d) * 2048 + kv0 + c * 8];
    }
  };

  loadKV(0);
  for (int kv0 = 0; kv0 < nkv; kv0 += 64) {
    __syncthreads();  // prior compute done before overwriting sK/sV
    u16* kbase = &sK[0][0];
#pragma unroll
    for (int i = 0; i < 6; ++i) *(u16x8*)&kbase[(size_t)(i * 256 + tid) * 8] = kreg[i];
    u16* vbase = &sV[0][0];
#pragma unroll
    for (int i = 0; i < 4; ++i) *(u16x8*)&vbase[(size_t)(i * 256 + tid) * 8] = vreg[i];
    __syncthreads();
    if (kv0 + 64 < nkv) loadKV(kv0 + 64);  // prefetch overlaps compute

    // S^ = Q K^T  (per wave: 32 q rows x 64 kv)
    f32x4 sc[2][4] = {};
#pragma unroll
    for (int kk = 0; kk < 6; ++kk) {
      u16x8 bfr[4];
#pragma unroll
      for (int n = 0; n < 4; ++n) bfr[n] = *(const u16x8*)&sK[n * 16 + lr][kk * 32 + lg * 8];
#pragma unroll
      for (int m = 0; m < 2; ++m)
#pragma unroll
        for (int n = 0; n < 4; ++n)
          sc[m][n] = mfma_bf16(qf[m][kk], bfr[n], sc[m][n]);
    }

    // causal mask
    if (kv0 + 63 > q0 + wid * 32) {
#pragma unroll
      for (int m = 0; m < 2; ++m)
#pragma unroll
        for (int n = 0; n < 4; ++n) {
          const int kv = kv0 + n * 16 + lr;
#pragma unroll
          for (int r = 0; r < 4; ++r) {
            const int rowq = q0 + wid * 32 + m * 16 + lg * 4 + r;
            if (kv > rowq) sc[m][n][r] = -1e30f;
          }
        }
    }

    // online softmax (rows live in (lg, reg); reduce across lr lanes)
#pragma unroll
    for (int m = 0; m < 2; ++m) {
      float rs[4];
#pragma unroll
      for (int r = 0; r < 4; ++r) {
        float v = fmaxf(fmaxf(sc[m][0][r], sc[m][1][r]), fmaxf(sc[m][2][r], sc[m][3][r]));
#pragma unroll
        for (int off = 1; off < 16; off <<= 1) v = fmaxf(v, __shfl_xor(v, off, 64));
        const float mnew = fmaxf(mx[m][r], v);
        const float alpha = __expf(mx[m][r] - mnew);
        mx[m][r] = mnew;
        ls[m][r] *= alpha;
#pragma unroll
        for (int df = 0; df < 8; ++df) acc[m][df][r] *= alpha;
        rs[r] = 0.f;
      }
#pragma unroll
      for (int n = 0; n < 4; ++n)
#pragma unroll
        for (int r = 0; r < 4; ++r) {
          const float p = __expf(sc[m][n][r] - mx[m][r]);
          rs[r] += p;
          sP[wid][m * 16 + lg * 4 + r][n * 16 + lr] = f2bf(p);
        }
#pragma unroll
      for (int r = 0; r < 4; ++r) {
        float v = rs[r];
#pragma unroll
        for (int off = 1; off < 16; off <<= 1) v += __shfl_xor(v, off, 64);
        ls[m][r] += v;
      }
    }

    // PV: acc += P * V
#pragma unroll
    for (int ks = 0; ks < 2; ++ks) {
      u16x8 pf0 = *(const u16x8*)&sP[wid][lr][ks * 32 + lg * 8];
      u16x8 pf1 = *(const u16x8*)&sP[wid][16 + lr][ks * 32 + lg * 8];
#pragma unroll
      for (int df = 0; df < 8; ++df) {
        u16x8 vf = *(const u16x8*)&sV[df * 16 + lr][ks * 32 + lg * 8];
        acc[0][df] = mfma_bf16(pf0, vf, acc[0][df]);
        acc[1][df] = mfma_bf16(pf1, vf, acc[1][df]);
      }
    }
  }

  // epilogue: attn(s, h*128+d) bf16
#pragma unroll
  for (int m = 0; m < 2; ++m)
#pragma unroll
    for (int df = 0; df < 8; ++df) {
      const int col = h * 128 + df * 16 + lr;
#pragma unroll
      for (int r = 0; r < 4; ++r) {
        const int row = q0 + wid * 32 + m * 16 + lg * 4 + r;
        attnb[(size_t)row * 4096 + col] = f2bf(acc[m][df][r] / ls[m][r]);
      }
    }
}

extern "C" void kernel_launch(void* const* d_in, const int* in_sizes, int n_in,
                              void* d_out, int out_size, void* d_ws, size_t ws_size,
                              hipStream_t stream) {
  (void)in_sizes; (void)n_in; (void)out_size; (void)ws_size;
  const float* hidden  = (const float*)d_in[0];
  const float* cosp    = (const float*)d_in[1];
  const float* sinp    = (const float*)d_in[2];
  const float* w_q_a   = (const float*)d_in[3];
  const float* q_a_ln  = (const float*)d_in[4];
  const float* w_q_b   = (const float*)d_in[5];
  const float* w_kv_a  = (const float*)d_in[6];
  const float* kv_a_ln = (const float*)d_in[7];
  const float* w_kv_b  = (const float*)d_in[8];
  const float* w_o     = (const float*)d_in[9];
  float* out = (float*)d_out;

  char* p = (char*)d_ws;
  auto alloc = [&](size_t bytes) { char* r = p; p += (bytes + 255) & ~(size_t)255; return r; };
  u16* Hb     = (u16*)alloc((size_t)S_LEN * HIDDEN_D * 2);
  u16* qlatn  = (u16*)alloc((size_t)S_LEN * QLORA * 2);
  u16* klatn  = (u16*)alloc((size_t)S_LEN * KVLORA * 2);
  u16* krot   = (u16*)alloc((size_t)S_LEN * ROPED * 2);
  u16* Qb     = (u16*)alloc((size_t)NHEADS * S_LEN * QHD * 2);
  u16* Knope  = (u16*)alloc((size_t)NHEADS * S_LEN * NOPED * 2);
  u16* Vt     = (u16*)alloc((size_t)NHEADS * VDIM * S_LEN * 2);
  u16* attnb  = (u16*)alloc((size_t)S_LEN * 4096 * 2);
  u16* Wqa    = (u16*)alloc((size_t)QLORA * HIDDEN_D * 2);
  u16* Wqb    = (u16*)alloc((size_t)6144 * QLORA * 2);
  u16* Wkva   = (u16*)alloc((size_t)576 * HIDDEN_D * 2);
  u16* Wkvb   = (u16*)alloc((size_t)8192 * KVLORA * 2);
  u16* Wo     = (u16*)alloc((size_t)HIDDEN_D * 4096 * 2);
  u16* qraw16 = (u16*)alloc((size_t)S_LEN * 6144 * 2);
  float* qa_part  = (float*)alloc((size_t)2 * S_LEN * QLORA * 4);  // 2 split-K partials
  float* kva_part = (float*)alloc((size_t)4 * S_LEN * 576 * 4);    // 4 split-K partials

  // 1. activations + weights -> bf16
  cvt_kernel<<<(S_LEN * HIDDEN_D / 4 + 255) / 256, 256, 0, stream>>>(hidden, Hb, S_LEN * HIDDEN_D / 4);
  cvt_kernel<<<(QLORA * HIDDEN_D / 4 + 255) / 256, 256, 0, stream>>>(w_q_a, Wqa, QLORA * HIDDEN_D / 4);
  cvt_kernel<<<(6144 * QLORA / 4 + 255) / 256, 256, 0, stream>>>(w_q_b, Wqb, 6144 * QLORA / 4);
  cvt_kernel<<<(576 * HIDDEN_D / 4 + 255) / 256, 256, 0, stream>>>(w_kv_a, Wkva, 576 * HIDDEN_D / 4);
  cvt_kernel<<<(8192 * KVLORA / 4 + 255) / 256, 256, 0, stream>>>(w_kv_b, Wkvb, 8192 * KVLORA / 4);
  cvt_kernel<<<(HIDDEN_D * 4096 / 4 + 255) / 256, 256, 0, stream>>>(w_o, Wo, HIDDEN_D * 4096 / 4);

  // 2. q_lat partials = Hb @ Wqa^T  (2048 x 1536, K=4096 split 2)
  gemm_ff<<<dim3(16 * 12, 2), 256, 0, stream>>>(Hb, Wqa, qa_part, 2048, 1536, 2048, 4096, 4096, 1536);
  // 3. ckv partials = Hb @ Wkva^T  (2048 x 576, K=4096 split 4)
  gemm_ff<<<dim3(16 * 5, 4), 256, 0, stream>>>(Hb, Wkva, kva_part, 2048, 576, 1024, 4096, 4096, 576);
  // 4. RMS(sum of q_lat partials) -> bf16
  rms_kernel<<<2048, 256, 0, stream>>>(qa_part, q_a_ln, qlatn, 1536, 2, (size_t)S_LEN * QLORA);
  // 5. RMS(sum of ckv partials) + rope(k_rot)
  ckv_epi_kernel<<<2048, 256, 0, stream>>>(kva_part, kv_a_ln, cosp, sinp, klatn, krot, 4, (size_t)S_LEN * 576);
  // 6. q = qlatn @ Wqb^T  (2048 x 6144, K=1536, bf16 out)
  gemm_fb<<<dim3(16 * 48, 1), 256, 0, stream>>>(qlatn, Wqb, qraw16, 2048, 6144, 1536, 1536, 1536, 6144);
  // 7. rope+scale+layout -> Qb
  q_epi_kernel<<<2048, 256, 0, stream>>>(qraw16, cosp, sinp, Qb);
  // 8. kv = klatn @ Wkvb^T with fused split+transpose -> Knope, Vt (bf16)
  gemm_kvb<<<dim3(16 * 64, 1), 256, 0, stream>>>(klatn, Wkvb, Knope, Vt, 2048, 8192, 512, 512, 512);
  // 9. causal flash attention (exact R8 known-good binary structure)
  flash_kernel<<<512, 256, 0, stream>>>(Qb, krot, Knope, Vt, attnb);
  // 10. out = attn @ Wo^T  (2048 x 4096, K=4096, fp32 out)
  gemm_ff<<<dim3(16 * 32, 1), 256, 0, stream>>>(attnb, Wo, out, 2048, 4096, 4096, 4096, 4096, 4096);
}

// Round 12
// 599.090 us; speedup vs baseline: 1.0636x; 1.0636x over previous
//
#include <hip/hip_runtime.h>

typedef unsigned short u16;
typedef u16 u16x4 __attribute__((ext_vector_type(4)));
typedef u16 u16x8 __attribute__((ext_vector_type(8)));
typedef float f32x4 __attribute__((ext_vector_type(4)));
typedef __bf16 bf16x8 __attribute__((ext_vector_type(8)));

#define S_LEN 2048
#define HIDDEN_D 4096
#define NHEADS 32
#define QLORA 1536
#define KVLORA 512
#define ROPED 64
#define NOPED 128
#define VDIM 128
#define QHD 192
#define SCALING_F 0.07216878364870323f

__device__ __forceinline__ u16 f2bf(float x) {
  union { float f; unsigned u; } v; v.f = x;
  unsigned r = v.u + 0x7fffu + ((v.u >> 16) & 1u);
  return (u16)(r >> 16);
}
__device__ __forceinline__ float bf2f(u16 x) {
  union { unsigned u; float f; } v; v.u = ((unsigned)x) << 16; return v.f;
}

__device__ __forceinline__ f32x4 mfma_bf16(u16x8 a, u16x8 b, f32x4 c) {
  return __builtin_amdgcn_mfma_f32_16x16x32_bf16(
      __builtin_bit_cast(bf16x8, a), __builtin_bit_cast(bf16x8, b), c, 0, 0, 0);
}

// ---------------- fp32 -> bf16 convert (vector) ----------------
__global__ __launch_bounds__(256) void cvt_kernel(const float* __restrict__ in,
                                                  u16* __restrict__ out, int n4) {
  int i = blockIdx.x * 256 + threadIdx.x;
  if (i >= n4) return;
  f32x4 v = ((const f32x4*)in)[i];
  u16x4 o;
  o[0] = f2bf(v[0]); o[1] = f2bf(v[1]); o[2] = f2bf(v[2]); o[3] = f2bf(v[3]);
  ((u16x4*)out)[i] = o;
}

// ============ GEMM core (R9-proven): A bf16 * B bf16^T, reg-staged dbuf LDS ============

#define GEMM_PROLOGUE()                                                        \
  __shared__ u16 sA[2][128 * 64];                                              \
  __shared__ u16 sB[2][128 * 64];                                              \
  const int tid = threadIdx.x;                                                 \
  const int wid = tid >> 6, lane = tid & 63;                                   \
  const int lr = lane & 15, lg = lane >> 4;                                    \
  const int nbn = (N + 127) >> 7;                                              \
  const int bx = blockIdx.x % nbn, by = blockIdx.x / nbn;                      \
  const int bm = by << 7, bn = bx << 7;                                        \
  const int wm = (wid >> 1) << 6, wn = (wid & 1) << 6;                         \
  const int kbase = blockIdx.y * Ks;                                           \
  f32x4 acc[4][4] = {};                                                        \
  u16x8 areg[4], breg[4];                                                      \
  auto loadA = [&](int k0) {                                                   \
    _Pragma("unroll")                                                          \
    for (int i = 0; i < 4; ++i) {                                              \
      int chunk = i * 256 + tid;                                               \
      int row = chunk >> 3, c8 = chunk & 7;                                    \
      int gr = bm + row; if (gr >= M) gr = M - 1;                              \
      areg[i] = *(const u16x8*)(A + (size_t)gr * lda + k0 + (c8 << 3));        \
    }                                                                          \
  };                                                                           \
  auto loadB = [&](int k0) {                                                   \
    _Pragma("unroll")                                                          \
    for (int i = 0; i < 4; ++i) {                                              \
      int chunk = i * 256 + tid;                                               \
      int n = chunk >> 3, c8 = chunk & 7;                                      \
      int gn = bn + n; if (gn >= N) gn = N - 1;                                \
      breg[i] = *(const u16x8*)(B + (size_t)gn * ldb + k0 + (c8 << 3));        \
    }                                                                          \
  };                                                                           \
  auto writeAB = [&](int buf) {                                                \
    _Pragma("unroll")                                                          \
    for (int i = 0; i < 4; ++i) {                                              \
      *(u16x8*)&sA[buf][(i * 256 + tid) * 8] = areg[i];                        \
      *(u16x8*)&sB[buf][(i * 256 + tid) * 8] = breg[i];                        \
    }                                                                          \
  };                                                                           \
  auto compute = [&](int buf) {                                                \
    const u16* pa = sA[buf];                                                   \
    const u16* pb = sB[buf];                                                   \
    _Pragma("unroll")                                                          \
    for (int ks = 0; ks < 2; ++ks) {                                           \
      const int kof = ks * 32 + lg * 8;                                        \
      u16x8 av[4], bv[4];                                                      \
      _Pragma("unroll")                                                        \
      for (int m = 0; m < 4; ++m) av[m] = *(const u16x8*)&pa[(wm + m * 16 + lr) * 64 + kof]; \
      _Pragma("unroll")                                                        \
      for (int n = 0; n < 4; ++n) bv[n] = *(const u16x8*)&pb[(wn + n * 16 + lr) * 64 + kof]; \
      _Pragma("unroll")                                                        \
      for (int m = 0; m < 4; ++m)                                              \
        _Pragma("unroll")                                                      \
        for (int n = 0; n < 4; ++n)                                            \
          acc[m][n] = mfma_bf16(av[m], bv[n], acc[m][n]);                      \
    }                                                                          \
  };                                                                           \
  const int nk = Ks >> 6;                                                      \
  loadA(kbase); loadB(kbase);                                                  \
  writeAB(0);                                                                  \
  __syncthreads();                                                             \
  for (int t = 0; t < nk; ++t) {                                               \
    const int cur = t & 1;                                                     \
    if (t + 1 < nk) { loadA(kbase + ((t + 1) << 6)); loadB(kbase + ((t + 1) << 6)); } \
    compute(cur);                                                              \
    if (t + 1 < nk) { writeAB(cur ^ 1); }                                      \
    __syncthreads();                                                           \
  }

// ---------------- GEMM -> fp32 C (fused q_a+kv_a, w_o) ----------------
__global__ __launch_bounds__(256, 2) void gemm_ff(
    const u16* __restrict__ A, const u16* __restrict__ B, float* __restrict__ C,
    int M, int N, int Ks, int lda, int ldb, int ldc)
{
  C += (size_t)blockIdx.y * M * ldc;
  GEMM_PROLOGUE()
#pragma unroll
  for (int m = 0; m < 4; ++m) {
    const int row0 = bm + wm + m * 16 + (lg << 2);
#pragma unroll
    for (int n = 0; n < 4; ++n) {
      const int col = bn + wn + n * 16 + lr;
      if (col < N) {
#pragma unroll
        for (int r = 0; r < 4; ++r)
          C[(size_t)(row0 + r) * ldc + col] = acc[m][n][r];
      }
    }
  }
}

// ---------------- GEMM -> bf16 C (q_b) ----------------
__global__ __launch_bounds__(256, 2) void gemm_fb(
    const u16* __restrict__ A, const u16* __restrict__ B, u16* __restrict__ C,
    int M, int N, int Ks, int lda, int ldb, int ldc)
{
  GEMM_PROLOGUE()
#pragma unroll
  for (int m = 0; m < 4; ++m) {
    const int row0 = bm + wm + m * 16 + (lg << 2);
#pragma unroll
    for (int n = 0; n < 4; ++n) {
      const int col = bn + wn + n * 16 + lr;
#pragma unroll
      for (int r = 0; r < 4; ++r)
        C[(size_t)(row0 + r) * ldc + col] = f2bf(acc[m][n][r]);
    }
  }
}

// ---------------- kv_b GEMM with fused split+transpose epilogue ----------------
// C[s][h*256+c]: c<128 -> Knope[(h*2048+s)*128+c]; c>=128 -> Vt[(h*128+c-128)*2048+s].
__global__ __launch_bounds__(256, 2) void gemm_kvb(
    const u16* __restrict__ A, const u16* __restrict__ B,
    u16* __restrict__ Knope, u16* __restrict__ Vt,
    int M, int N, int Ks, int lda, int ldb)
{
  GEMM_PROLOGUE()
#pragma unroll
  for (int m = 0; m < 4; ++m) {
    const int row0 = bm + wm + m * 16 + (lg << 2);
#pragma unroll
    for (int n = 0; n < 4; ++n) {
      const int col = bn + wn + n * 16 + lr;
      const int h = col >> 8, c = col & 255;
      if (c < 128) {
#pragma unroll
        for (int r = 0; r < 4; ++r)
          Knope[((size_t)h * 2048 + row0 + r) * 128 + c] = f2bf(acc[m][n][r]);
      } else {
        u16x4 v;
        v[0] = f2bf(acc[m][n][0]); v[1] = f2bf(acc[m][n][1]);
        v[2] = f2bf(acc[m][n][2]); v[3] = f2bf(acc[m][n][3]);
        *(u16x4*)&Vt[((size_t)h * 128 + (c - 128)) * 2048 + row0] = v;
      }
    }
  }
}

// ---------------- RMS norm rows over summed split-K partials (fp32 -> bf16) ----------------
__global__ __launch_bounds__(256) void rms_kernel(const float* __restrict__ X,
                                                  const float* __restrict__ w,
                                                  u16* __restrict__ out, int D, int ldx,
                                                  int nparts, size_t pstride) {
  const int row = blockIdx.x;
  const float* x = X + (size_t)row * ldx;
  __shared__ float sb[4];
  float ss = 0.f;
  for (int i = threadIdx.x * 4; i < D; i += 1024) {
    f32x4 v = *(const f32x4*)&x[i];
    for (int pp = 1; pp < nparts; ++pp) {
      f32x4 v2 = *(const f32x4*)&x[pp * pstride + i];
      v[0] += v2[0]; v[1] += v2[1]; v[2] += v2[2]; v[3] += v2[3];
    }
    ss += v[0] * v[0] + v[1] * v[1] + v[2] * v[2] + v[3] * v[3];
  }
#pragma unroll
  for (int off = 32; off >= 1; off >>= 1) ss += __shfl_xor(ss, off, 64);
  if ((threadIdx.x & 63) == 0) sb[threadIdx.x >> 6] = ss;
  __syncthreads();
  const float inv = rsqrtf((sb[0] + sb[1] + sb[2] + sb[3]) / (float)D + 1e-6f);
  u16* o = out + (size_t)row * D;
  for (int i = threadIdx.x * 4; i < D; i += 1024) {
    f32x4 v = *(const f32x4*)&x[i];
    for (int pp = 1; pp < nparts; ++pp) {
      f32x4 v2 = *(const f32x4*)&x[pp * pstride + i];
      v[0] += v2[0]; v[1] += v2[1]; v[2] += v2[2]; v[3] += v2[3];
    }
    f32x4 wv = *(const f32x4*)&w[i];
    u16x4 u;
    u[0] = f2bf(v[0] * inv * wv[0]); u[1] = f2bf(v[1] * inv * wv[1]);
    u[2] = f2bf(v[2] * inv * wv[2]); u[3] = f2bf(v[3] * inv * wv[3]);
    *(u16x4*)&o[i] = u;
  }
}

// ---------------- ckv epilogue over split-K partials: RMS(512) + rope(64) ----------------
__global__ __launch_bounds__(256) void ckv_epi_kernel(const float* __restrict__ ckv,
    const float* __restrict__ w, const float* __restrict__ cosp, const float* __restrict__ sinp,
    u16* __restrict__ klatn, u16* __restrict__ krot, int ldx, int nparts, size_t pstride) {
  const int s = blockIdx.x;
  const float* x = ckv + (size_t)s * ldx;
  __shared__ float sb[4];
  const int i2 = threadIdx.x * 2;
  float a = 0.f, b = 0.f;
  for (int pp = 0; pp < nparts; ++pp) {
    a += x[pp * pstride + i2];
    b += x[pp * pstride + i2 + 1];
  }
  float ss = a * a + b * b;
#pragma unroll
  for (int off = 32; off >= 1; off >>= 1) ss += __shfl_xor(ss, off, 64);
  if ((threadIdx.x & 63) == 0) sb[threadIdx.x >> 6] = ss;
  __syncthreads();
  const float inv = rsqrtf((sb[0] + sb[1] + sb[2] + sb[3]) / 512.0f + 1e-6f);
  klatn[(size_t)s * 512 + i2]     = f2bf(a * inv * w[i2]);
  klatn[(size_t)s * 512 + i2 + 1] = f2bf(b * inv * w[i2 + 1]);
  if (threadIdx.x < 64) {
    const int d = threadIdx.x;
    float xr = 0.f, rrabs = 0.f;
    for (int pp = 0; pp < nparts; ++pp) {
      xr += x[pp * pstride + 512 + d];
      rrabs += x[pp * pstride + 512 + ((d < 32) ? (d + 32) : (d - 32))];
    }
    const float rr = (d < 32) ? -rrabs : rrabs;
    krot[(size_t)s * 64 + d] = f2bf(xr * cosp[s * 64 + d] + rr * sinp[s * 64 + d]);
  }
}

// ---------------- q epilogue (bf16 in): rope + scale + [rope|nope] layout, bf16 ----------------
__global__ __launch_bounds__(256) void q_epi_kernel(const u16* __restrict__ q_raw,
    const float* __restrict__ cosp, const float* __restrict__ sinp, u16* __restrict__ Qb) {
  const int s = blockIdx.x;
  const u16* x = q_raw + (size_t)s * 6144;
  for (int idx = threadIdx.x; idx < 6144; idx += 256) {
    const int h = idx / 192, d = idx - h * 192;
    float v;
    if (d < 64) {
      const float xr = bf2f(x[h * 192 + 128 + d]);
      const float rr = (d < 32) ? -bf2f(x[h * 192 + 160 + d]) : bf2f(x[h * 192 + 96 + d]);
      v = xr * cosp[s * 64 + d] + rr * sinp[s * 64 + d];
    } else {
      v = bf2f(x[h * 192 + d - 64]);
    }
    Qb[((size_t)h * 2048 + s) * QHD + d] = f2bf(v * SCALING_F);
  }
}

// ---------------- flash attention (causal), 4 waves, QBLK=128, KVBLK=64 ----------------
// EXACT R1/R8 structure (measured 250us / 40MB fetch): linear LDS, natural block
// order, no setprio, no barrier. DO NOT MODIFY — fragile cache-lockstep regime.
__global__ __launch_bounds__(256, 2) void flash_kernel(
    const u16* __restrict__ Qb, const u16* __restrict__ Krot,
    const u16* __restrict__ Knope, const u16* __restrict__ Vt,
    u16* __restrict__ attnb)
{
  const int h = blockIdx.x & 31, qt = blockIdx.x >> 5;
  const int q0 = qt << 7;
  __shared__ u16 sK[64][QHD];      // [kv][rope(64)|nope(128)]
  __shared__ u16 sV[VDIM][64];     // V^T [d][kv]
  __shared__ u16 sP[4][32][64];    // per-wave P
  const int tid = threadIdx.x;
  const int wid = tid >> 6, lane = tid & 63;
  const int lr = lane & 15, lg = lane >> 4;

  u16x8 qf[2][6];
#pragma unroll
  for (int m = 0; m < 2; ++m) {
    const int row = q0 + wid * 32 + m * 16 + lr;
#pragma unroll
    for (int kk = 0; kk < 6; ++kk)
      qf[m][kk] = *(const u16x8*)&Qb[((size_t)h * 2048 + row) * QHD + kk * 32 + lg * 8];
  }

  f32x4 acc[2][8] = {};
  float mx[2][4], ls[2][4];
#pragma unroll
  for (int m = 0; m < 2; ++m)
#pragma unroll
    for (int r = 0; r < 4; ++r) { mx[m][r] = -1e30f; ls[m][r] = 0.f; }

  const int nkv = q0 + 128;
  u16x8 kreg[6], vreg[4];

  auto loadKV = [&](int kv0) {
#pragma unroll
    for (int i = 0; i < 6; ++i) {
      const int chunk = i * 256 + tid;
      const int row = chunk / 24, cc = chunk % 24;
      const u16* src = (cc < 8)
          ? &Krot[(size_t)(kv0 + row) * 64 + cc * 8]
          : &Knope[((size_t)h * 2048 + kv0 + row) * 128 + (cc - 8) * 8];
      kreg[i] = *(const u16x8*)src;
    }
#pragma unroll
    for (int i = 0; i < 4; ++i) {
      const int chunk = i * 256 + tid;
      const int d = chunk >> 3, c = chunk & 7;
      vreg[i] = *(const u16x8*)&Vt[((size_t)h * VDIM + d) * 2048 + kv0 + c * 8];
    }
  };

  loadKV(0);
  for (int kv0 = 0; kv0 < nkv; kv0 += 64) {
    __syncthreads();  // prior compute done before overwriting sK/sV
    u16* kbase = &sK[0][0];
#pragma unroll
    for (int i = 0; i < 6; ++i) *(u16x8*)&kbase[(size_t)(i * 256 + tid) * 8] = kreg[i];
    u16* vbase = &sV[0][0];
#pragma unroll
    for (int i = 0; i < 4; ++i) *(u16x8*)&vbase[(size_t)(i * 256 + tid) * 8] = vreg[i];
    __syncthreads();
    if (kv0 + 64 < nkv) loadKV(kv0 + 64);  // prefetch overlaps compute

    // S^ = Q K^T  (per wave: 32 q rows x 64 kv)
    f32x4 sc[2][4] = {};
#pragma unroll
    for (int kk = 0; kk < 6; ++kk) {
      u16x8 bfr[4];
#pragma unroll
      for (int n = 0; n < 4; ++n) bfr[n] = *(const u16x8*)&sK[n * 16 + lr][kk * 32 + lg * 8];
#pragma unroll
      for (int m = 0; m < 2; ++m)
#pragma unroll
        for (int n = 0; n < 4; ++n)
          sc[m][n] = mfma_bf16(qf[m][kk], bfr[n], sc[m][n]);
    }

    // causal mask
    if (kv0 + 63 > q0 + wid * 32) {
#pragma unroll
      for (int m = 0; m < 2; ++m)
#pragma unroll
        for (int n = 0; n < 4; ++n) {
          const int kv = kv0 + n * 16 + lr;
#pragma unroll
          for (int r = 0; r < 4; ++r) {
            const int rowq = q0 + wid * 32 + m * 16 + lg * 4 + r;
            if (kv > rowq) sc[m][n][r] = -1e30f;
          }
        }
    }

    // online softmax (rows live in (lg, reg); reduce across lr lanes)
#pragma unroll
    for (int m = 0; m < 2; ++m) {
      float rs[4];
#pragma unroll
      for (int r = 0; r < 4; ++r) {
        float v = fmaxf(fmaxf(sc[m][0][r], sc[m][1][r]), fmaxf(sc[m][2][r], sc[m][3][r]));
#pragma unroll
        for (int off = 1; off < 16; off <<= 1) v = fmaxf(v, __shfl_xor(v, off, 64));
        const float mnew = fmaxf(mx[m][r], v);
        const float alpha = __expf(mx[m][r] - mnew);
        mx[m][r] = mnew;
        ls[m][r] *= alpha;
#pragma unroll
        for (int df = 0; df < 8; ++df) acc[m][df][r] *= alpha;
        rs[r] = 0.f;
      }
#pragma unroll
      for (int n = 0; n < 4; ++n)
#pragma unroll
        for (int r = 0; r < 4; ++r) {
          const float p = __expf(sc[m][n][r] - mx[m][r]);
          rs[r] += p;
          sP[wid][m * 16 + lg * 4 + r][n * 16 + lr] = f2bf(p);
        }
#pragma unroll
      for (int r = 0; r < 4; ++r) {
        float v = rs[r];
#pragma unroll
        for (int off = 1; off < 16; off <<= 1) v += __shfl_xor(v, off, 64);
        ls[m][r] += v;
      }
    }

    // PV: acc += P * V
#pragma unroll
    for (int ks = 0; ks < 2; ++ks) {
      u16x8 pf0 = *(const u16x8*)&sP[wid][lr][ks * 32 + lg * 8];
      u16x8 pf1 = *(const u16x8*)&sP[wid][16 + lr][ks * 32 + lg * 8];
#pragma unroll
      for (int df = 0; df < 8; ++df) {
        u16x8 vf = *(const u16x8*)&sV[df * 16 + lr][ks * 32 + lg * 8];
        acc[0][df] = mfma_bf16(pf0, vf, acc[0][df]);
        acc[1][df] = mfma_bf16(pf1, vf, acc[1][df]);
      }
    }
  }

  // epilogue: attn(s, h*128+d) bf16
#pragma unroll
  for (int m = 0; m < 2; ++m)
#pragma unroll
    for (int df = 0; df < 8; ++df) {
      const int col = h * 128 + df * 16 + lr;
#pragma unroll
      for (int r = 0; r < 4; ++r) {
        const int row = q0 + wid * 32 + m * 16 + lg * 4 + r;
        attnb[(size_t)row * 4096 + col] = f2bf(acc[m][df][r] / ls[m][r]);
      }
    }
}

extern "C" void kernel_launch(void* const* d_in, const int* in_sizes, int n_in,
                              void* d_out, int out_size, void* d_ws, size_t ws_size,
                              hipStream_t stream) {
  (void)in_sizes; (void)n_in; (void)out_size; (void)ws_size;
  const float* hidden  = (const float*)d_in[0];
  const float* cosp    = (const float*)d_in[1];
  const float* sinp    = (const float*)d_in[2];
  const float* w_q_a   = (const float*)d_in[3];
  const float* q_a_ln  = (const float*)d_in[4];
  const float* w_q_b   = (const float*)d_in[5];
  const float* w_kv_a  = (const float*)d_in[6];
  const float* kv_a_ln = (const float*)d_in[7];
  const float* w_kv_b  = (const float*)d_in[8];
  const float* w_o     = (const float*)d_in[9];
  float* out = (float*)d_out;

  char* p = (char*)d_ws;
  auto alloc = [&](size_t bytes) { char* r = p; p += (bytes + 255) & ~(size_t)255; return r; };
  u16* Hb      = (u16*)alloc((size_t)S_LEN * HIDDEN_D * 2);
  u16* qlatn   = (u16*)alloc((size_t)S_LEN * QLORA * 2);
  u16* klatn   = (u16*)alloc((size_t)S_LEN * KVLORA * 2);
  u16* krot    = (u16*)alloc((size_t)S_LEN * ROPED * 2);
  u16* Qb      = (u16*)alloc((size_t)NHEADS * S_LEN * QHD * 2);
  u16* Knope   = (u16*)alloc((size_t)NHEADS * S_LEN * NOPED * 2);
  u16* Vt      = (u16*)alloc((size_t)NHEADS * VDIM * S_LEN * 2);
  u16* attnb   = (u16*)alloc((size_t)S_LEN * 4096 * 2);
  u16* WqaKva  = (u16*)alloc((size_t)2112 * HIDDEN_D * 2);   // [w_q_a(1536); w_kv_a(576)]
  u16* Wqb     = (u16*)alloc((size_t)6144 * QLORA * 2);
  u16* Wkvb    = (u16*)alloc((size_t)8192 * KVLORA * 2);
  u16* Wo      = (u16*)alloc((size_t)HIDDEN_D * 4096 * 2);
  u16* qraw16  = (u16*)alloc((size_t)S_LEN * 6144 * 2);
  float* qkv_part = (float*)alloc((size_t)2 * S_LEN * 2112 * 4);  // 2 split-K partials

  // 1. activations + weights -> bf16 (w_q_a and w_kv_a into one contiguous B)
  cvt_kernel<<<(S_LEN * HIDDEN_D / 4 + 255) / 256, 256, 0, stream>>>(hidden, Hb, S_LEN * HIDDEN_D / 4);
  cvt_kernel<<<(QLORA * HIDDEN_D / 4 + 255) / 256, 256, 0, stream>>>(w_q_a, WqaKva, QLORA * HIDDEN_D / 4);
  cvt_kernel<<<(576 * HIDDEN_D / 4 + 255) / 256, 256, 0, stream>>>(w_kv_a, WqaKva + (size_t)QLORA * HIDDEN_D, 576 * HIDDEN_D / 4);
  cvt_kernel<<<(6144 * QLORA / 4 + 255) / 256, 256, 0, stream>>>(w_q_b, Wqb, 6144 * QLORA / 4);
  cvt_kernel<<<(8192 * KVLORA / 4 + 255) / 256, 256, 0, stream>>>(w_kv_b, Wkvb, 8192 * KVLORA / 4);
  cvt_kernel<<<(HIDDEN_D * 4096 / 4 + 255) / 256, 256, 0, stream>>>(w_o, Wo, HIDDEN_D * 4096 / 4);

  // 2. fused [q_lat | ckv] partials = Hb @ WqaKva^T  (2048 x 2112, K=4096 split 2)
  gemm_ff<<<dim3(16 * 17, 2), 256, 0, stream>>>(Hb, WqaKva, qkv_part, 2048, 2112, 2048, 4096, 4096, 2112);
  // 3. RMS(sum of q_lat partials, cols 0..1535) -> bf16
  rms_kernel<<<2048, 256, 0, stream>>>(qkv_part, q_a_ln, qlatn, 1536, 2112, 2, (size_t)S_LEN * 2112);
  // 4. RMS(sum of ckv partials, cols 1536..2111) + rope(k_rot)
  ckv_epi_kernel<<<2048, 256, 0, stream>>>(qkv_part + 1536, kv_a_ln, cosp, sinp, klatn, krot, 2112, 2, (size_t)S_LEN * 2112);
  // 5. q = qlatn @ Wqb^T  (2048 x 6144, K=1536, bf16 out)
  gemm_fb<<<dim3(16 * 48, 1), 256, 0, stream>>>(qlatn, Wqb, qraw16, 2048, 6144, 1536, 1536, 1536, 6144);
  // 6. rope+scale+layout -> Qb
  q_epi_kernel<<<2048, 256, 0, stream>>>(qraw16, cosp, sinp, Qb);
  // 7. kv = klatn @ Wkvb^T with fused split+transpose -> Knope, Vt (bf16)
  gemm_kvb<<<dim3(16 * 64, 1), 256, 0, stream>>>(klatn, Wkvb, Knope, Vt, 2048, 8192, 512, 512, 512);
  // 8. causal flash attention (exact R8 known-good binary structure)
  flash_kernel<<<512, 256, 0, stream>>>(Qb, krot, Knope, Vt, attnb);
  // 9. out = attn @ Wo^T  (2048 x 4096, K=4096, fp32 out)
  gemm_ff<<<dim3(16 * 32, 1), 256, 0, stream>>>(attnb, Wo, out, 2048, 4096, 4096, 4096, 4096, 4096);
}